// Round 1
// baseline (2994.036 us; speedup 1.0000x reference)
//
#include <hip/hip_runtime.h>
#include <math.h>

#define NN 100000
#define NE 3200000
#define NG 512

// ---------------- vector helpers ----------------
template<int VEC> struct VT;
template<> struct VT<4>{ using T = float4; };
template<> struct VT<2>{ using T = float2; };
template<> struct VT<1>{ using T = float;  };

__device__ __forceinline__ float4 vfma(float4 a, float w, float4 b){
  a.x=fmaf(w,b.x,a.x); a.y=fmaf(w,b.y,a.y); a.z=fmaf(w,b.z,a.z); a.w=fmaf(w,b.w,a.w); return a; }
__device__ __forceinline__ float2 vfma(float2 a, float w, float2 b){
  a.x=fmaf(w,b.x,a.x); a.y=fmaf(w,b.y,a.y); return a; }
__device__ __forceinline__ float  vfma(float a, float w, float b){ return fmaf(w,b,a); }

__device__ __forceinline__ float4 vscale(float4 a, float w){ a.x*=w;a.y*=w;a.z*=w;a.w*=w; return a; }
__device__ __forceinline__ float2 vscale(float2 a, float w){ a.x*=w;a.y*=w; return a; }
__device__ __forceinline__ float  vscale(float a, float w){ return a*w; }

__device__ __forceinline__ float4 vadd(float4 a, float4 b){ a.x+=b.x;a.y+=b.y;a.z+=b.z;a.w+=b.w; return a; }
__device__ __forceinline__ float2 vadd(float2 a, float2 b){ a.x+=b.x;a.y+=b.y; return a; }
__device__ __forceinline__ float  vadd(float a, float b){ return a+b; }

__device__ __forceinline__ float4 vrelu(float4 a){ a.x=fmaxf(a.x,0.f);a.y=fmaxf(a.y,0.f);a.z=fmaxf(a.z,0.f);a.w=fmaxf(a.w,0.f); return a; }
__device__ __forceinline__ float2 vrelu(float2 a){ a.x=fmaxf(a.x,0.f);a.y=fmaxf(a.y,0.f); return a; }
__device__ __forceinline__ float  vrelu(float a){ return fmaxf(a,0.f); }

// ---------------- prep kernels ----------------
__global__ void hist_dst_k(const int* __restrict__ ei, int* __restrict__ deg){
  int e = blockIdx.x*256 + threadIdx.x;
  if (e < NE) atomicAdd(&deg[ei[NE + e]], 1);
}
__global__ void dinv_k(const int* __restrict__ deg, float* __restrict__ dinv){
  int i = blockIdx.x*256 + threadIdx.x;
  if (i < NN) dinv[i] = rsqrtf((float)(deg[i] + 1));   // +1 = self loop
}
// single-block exclusive scan of deg -> row_ptr[NN+1]
__global__ void scan_k(const int* __restrict__ deg, int* __restrict__ rp){
  __shared__ int sums[1024];
  int tid = threadIdx.x;
  const int chunk = (NN + 1023)/1024;
  int b = tid*chunk, e = min(b+chunk, NN);
  int s = 0;
  for (int i=b;i<e;i++) s += deg[i];
  sums[tid] = s; __syncthreads();
  for (int off=1; off<1024; off<<=1){
    int v = (tid>=off) ? sums[tid-off] : 0;
    __syncthreads();
    sums[tid] += v;
    __syncthreads();
  }
  int run = (tid>0) ? sums[tid-1] : 0;
  for (int i=b;i<e;i++){ rp[i] = run; run += deg[i]; }
  if (tid==1023) rp[NN] = sums[1023];
}
__global__ void scatter_k(const int* __restrict__ ei, const int* __restrict__ rp,
                          int* __restrict__ cur, int* __restrict__ col){
  int e = blockIdx.x*256 + threadIdx.x;
  if (e < NE){
    int d = ei[NE + e];
    int pos = rp[d] + atomicAdd(&cur[d], 1);
    col[pos] = ei[e];
  }
}
__global__ void cnt_k(const int* __restrict__ batch, int* __restrict__ cnt){
  int i = blockIdx.x*256 + threadIdx.x;
  if (i < NN) atomicAdd(&cnt[batch[i]], 1);
}

// ---------------- SpMM: out[i] = dinv[i]*(sum_{nbr} in[src] + in[i]) [+bias][relu] ----------------
// Input rows are expected pre-scaled by dinv (GEMM epilogue), except SRC_SCALE layer-1 path
// which multiplies dinv[src] at gather time (input = raw x).
// 4 rows per 256-thread block, one wave per row, VEC = C/64 channels per lane.
template<int C, bool SRC_SCALE, bool RELU, bool HAS_BIAS>
__global__ __launch_bounds__(256) void spmm_k(const float* __restrict__ in, float* __restrict__ out,
    const int* __restrict__ rp, const int* __restrict__ col,
    const float* __restrict__ dinv, const float* __restrict__ bias)
{
  constexpr int VEC = C/64;
  using T = typename VT<VEC>::T;
  int wv = threadIdx.x >> 6, lane = threadIdx.x & 63;
  int row = blockIdx.x*4 + wv;
  if (row >= NN) return;
  int beg = rp[row], end = rp[row+1];
  float di = dinv[row];
  int co = lane*VEC;
  T acc = *(const T*)(in + (size_t)row*C + co);   // self loop
  if (SRC_SCALE) acc = vscale(acc, di);
  int j = beg;
  for (; j+4 <= end; j += 4){
    int s0=col[j+0], s1=col[j+1], s2=col[j+2], s3=col[j+3];
    T v0 = *(const T*)(in + (size_t)s0*C + co);
    T v1 = *(const T*)(in + (size_t)s1*C + co);
    T v2 = *(const T*)(in + (size_t)s2*C + co);
    T v3 = *(const T*)(in + (size_t)s3*C + co);
    float w0=1.f,w1=1.f,w2=1.f,w3=1.f;
    if (SRC_SCALE){ w0=dinv[s0]; w1=dinv[s1]; w2=dinv[s2]; w3=dinv[s3]; }
    acc = vfma(acc,w0,v0); acc = vfma(acc,w1,v1);
    acc = vfma(acc,w2,v2); acc = vfma(acc,w3,v3);
  }
  for (; j < end; j++){
    int s = col[j];
    T v = *(const T*)(in + (size_t)s*C + co);
    acc = vfma(acc, SRC_SCALE ? dinv[s] : 1.f, v);
  }
  acc = vscale(acc, di);
  if (HAS_BIAS) acc = vadd(acc, *(const T*)(bias + co));
  if (RELU) acc = vrelu(acc);
  *(T*)(out + (size_t)row*C + co) = acc;
}

// ---------------- fp32 GEMM: C = A[M,K] @ W[K,N], epilogue EPI=0: +bias,relu  EPI=1: *dinv[row] ----------------
template<int EPI>
__global__ __launch_bounds__(256) void gemm_k(const float* __restrict__ A, const float* __restrict__ W,
    const float* __restrict__ aux, float* __restrict__ Cm, int M, int K, int N)
{
  __shared__ float As[16][64];
  __shared__ float Bs[16][64];
  int tid = threadIdx.x;
  int m0 = blockIdx.x*64, n0 = blockIdx.y*64;
  int tx = tid & 15, ty = tid >> 4;          // 4x4 micro-tile: rows ty*4.., cols tx*4..
  int alr = tid >> 2, akc = (tid & 3)*4;     // A tile load: row alr, k-vec akc
  int bn = (tid & 15)*4, bk = tid >> 4;      // W tile load
  float4 acc[4];
  #pragma unroll
  for (int i=0;i<4;i++) acc[i] = make_float4(0.f,0.f,0.f,0.f);

  for (int k0=0; k0<K; k0+=16){
    float4 av = make_float4(0.f,0.f,0.f,0.f);
    if (m0 + alr < M) av = *(const float4*)&A[(size_t)(m0+alr)*K + k0 + akc];
    float4 bv = *(const float4*)&W[(size_t)(k0+bk)*N + n0 + bn];
    __syncthreads();
    As[akc+0][alr]=av.x; As[akc+1][alr]=av.y; As[akc+2][alr]=av.z; As[akc+3][alr]=av.w;
    *(float4*)&Bs[bk][bn] = bv;
    __syncthreads();
    #pragma unroll
    for (int k=0;k<16;k++){
      float4 a = *(const float4*)&As[k][ty*4];
      float4 b = *(const float4*)&Bs[k][tx*4];
      acc[0].x=fmaf(a.x,b.x,acc[0].x); acc[0].y=fmaf(a.x,b.y,acc[0].y); acc[0].z=fmaf(a.x,b.z,acc[0].z); acc[0].w=fmaf(a.x,b.w,acc[0].w);
      acc[1].x=fmaf(a.y,b.x,acc[1].x); acc[1].y=fmaf(a.y,b.y,acc[1].y); acc[1].z=fmaf(a.y,b.z,acc[1].z); acc[1].w=fmaf(a.y,b.w,acc[1].w);
      acc[2].x=fmaf(a.z,b.x,acc[2].x); acc[2].y=fmaf(a.z,b.y,acc[2].y); acc[2].z=fmaf(a.z,b.z,acc[2].z); acc[2].w=fmaf(a.z,b.w,acc[2].w);
      acc[3].x=fmaf(a.w,b.x,acc[3].x); acc[3].y=fmaf(a.w,b.y,acc[3].y); acc[3].z=fmaf(a.w,b.z,acc[3].z); acc[3].w=fmaf(a.w,b.w,acc[3].w);
    }
  }
  #pragma unroll
  for (int i=0;i<4;i++){
    int m = m0 + ty*4 + i;
    if (m < M){
      float4 v = acc[i];
      if (EPI == 0){
        float4 bb = *(const float4*)&aux[n0 + tx*4];
        v = vrelu(vadd(v, bb));
      } else {
        v = vscale(v, aux[m]);
      }
      *(float4*)&Cm[(size_t)m*N + n0 + tx*4] = v;
    }
  }
}

// ---------------- pooling + head ----------------
__global__ void pool_k(const float* __restrict__ h, const int* __restrict__ batch, float* __restrict__ pooled){
  int idx = blockIdx.x*256 + threadIdx.x;
  if (idx < NN*64){
    int node = idx >> 6, c = idx & 63;
    atomicAdd(&pooled[batch[node]*64 + c], h[idx]);
  }
}
__global__ void final_k(const float* __restrict__ pooled, const int* __restrict__ cnt,
    const float* __restrict__ Wlin, const float* __restrict__ blin, float* __restrict__ out)
{
  int g = blockIdx.x*256 + threadIdx.x;
  if (g >= NG) return;
  float inv = 1.f / fmaxf((float)cnt[g], 1.f);
  float l[10];
  #pragma unroll
  for (int j=0;j<10;j++) l[j] = blin[j];
  for (int c=0;c<64;c++){
    float p = pooled[g*64 + c] * inv;
    #pragma unroll
    for (int j=0;j<10;j++) l[j] = fmaf(p, Wlin[c*10 + j], l[j]);
  }
  float mx = l[0];
  #pragma unroll
  for (int j=1;j<10;j++) mx = fmaxf(mx, l[j]);
  float e[10]; float se = 0.f;
  #pragma unroll
  for (int j=0;j<10;j++){ e[j] = expf(l[j]-mx); se += e[j]; }
  float lse = logf(se);
  #pragma unroll
  for (int j=0;j<10;j++){
    out[g*10 + j]         = l[j] - mx - lse;   // log_softmax
    out[NG*10 + g*10 + j] = e[j] / se;         // softmax
  }
}

// ---------------- launch ----------------
extern "C" void kernel_launch(void* const* d_in, const int* in_sizes, int n_in,
                              void* d_out, int out_size, void* d_ws, size_t ws_size,
                              hipStream_t stream)
{
  const float* x     = (const float*)d_in[0];
  const int*   ei    = (const int*)  d_in[1];
  const int*   batch = (const int*)  d_in[2];
  const float* W1=(const float*)d_in[4],  *b1=(const float*)d_in[5];
  const float* W2=(const float*)d_in[6],  *b2=(const float*)d_in[7];
  const float* W3=(const float*)d_in[8],  *b3=(const float*)d_in[9];
  const float* W4=(const float*)d_in[10], *b4=(const float*)d_in[11];
  const float* W5=(const float*)d_in[12], *b5=(const float*)d_in[13];
  const float* W6=(const float*)d_in[14], *b6=(const float*)d_in[15];
  const float* Wl=(const float*)d_in[16], *bl=(const float*)d_in[17];
  float* out = (float*)d_out;

  // workspace carve (all offsets 16B aligned); total ~219.4 MB
  char* ws = (char*)d_ws;
  float* Abuf  = (float*)(ws + 0);                    // 100000*256*4 = 102,400,000
  float* Bbuf  = (float*)(ws + 102400000);            // 102,400,000
  int*   rp    = (int*)  (ws + 204800000);            // 400,016
  int*   deg   = (int*)  (ws + 205200016);            // 400,000
  int*   cur   = (int*)  (ws + 205600016);            // 400,000
  float* dinv  = (float*)(ws + 206000016);            // 400,000
  int*   col   = (int*)  (ws + 206400016);            // 12,800,000
  float* pooled= (float*)(ws + 219200016);            // 131,072
  int*   cnt   = (int*)  (ws + 219331088);            // 2,048

  hipMemsetAsync(deg,    0, NN*4,      stream);
  hipMemsetAsync(cur,    0, NN*4,      stream);
  hipMemsetAsync(pooled, 0, NG*64*4,   stream);
  hipMemsetAsync(cnt,    0, NG*4,      stream);

  const int EB = (NE + 255)/256, NB = (NN + 255)/256;
  hist_dst_k<<<EB, 256, 0, stream>>>(ei, deg);
  dinv_k    <<<NB, 256, 0, stream>>>(deg, dinv);
  scan_k    <<<1, 1024, 0, stream>>>(deg, rp);
  scatter_k <<<EB, 256, 0, stream>>>(ei, rp, cur, col);
  cnt_k     <<<NB, 256, 0, stream>>>(batch, cnt);

  const int SG = (NN + 3)/4;                 // spmm grid: 4 rows/block
  dim3 g4((NN+63)/64, 4), g2((NN+63)/64, 2), g1b((NN+63)/64, 1);

  // L1: aggregate-first at width 128 (Âx), then GEMM 128->256 (+b1, relu)
  spmm_k<128,true,false,false><<<SG,256,0,stream>>>(x, Abuf, rp, col, dinv, nullptr);
  gemm_k<0><<<g4,256,0,stream>>>(Abuf, W1, b1, Bbuf, NN, 128, 256);
  // L2: GEMM 256->256 (*dinv), SpMM (+b2, relu)
  gemm_k<1><<<g4,256,0,stream>>>(Bbuf, W2, dinv, Abuf, NN, 256, 256);
  spmm_k<256,false,true,true><<<SG,256,0,stream>>>(Abuf, Bbuf, rp, col, dinv, b2);
  // L3
  gemm_k<1><<<g4,256,0,stream>>>(Bbuf, W3, dinv, Abuf, NN, 256, 256);
  spmm_k<256,false,true,true><<<SG,256,0,stream>>>(Abuf, Bbuf, rp, col, dinv, b3);
  // L4: 256->128
  gemm_k<1><<<g2,256,0,stream>>>(Bbuf, W4, dinv, Abuf, NN, 256, 128);
  spmm_k<128,false,true,true><<<SG,256,0,stream>>>(Abuf, Bbuf, rp, col, dinv, b4);
  // L5: 128->128
  gemm_k<1><<<g2,256,0,stream>>>(Bbuf, W5, dinv, Abuf, NN, 128, 128);
  spmm_k<128,false,true,true><<<SG,256,0,stream>>>(Abuf, Bbuf, rp, col, dinv, b5);
  // L6: 128->64, no relu
  gemm_k<1><<<g1b,256,0,stream>>>(Bbuf, W6, dinv, Abuf, NN, 128, 64);
  spmm_k<64,false,false,true><<<SG,256,0,stream>>>(Abuf, Bbuf, rp, col, dinv, b6);

  // mean pool + linear + (log_)softmax
  pool_k <<<(NN*64 + 255)/256, 256, 0, stream>>>(Bbuf, batch, pooled);
  final_k<<<2, 256, 0, stream>>>(pooled, cnt, Wl, bl, out);
}

// Round 2
// 1900.243 us; speedup vs baseline: 1.5756x; 1.5756x over previous
//
#include <hip/hip_runtime.h>
#include <math.h>

#define NN 100000
#define NE 3200000
#define NG 512

typedef __attribute__((ext_vector_type(8))) short short8;
typedef __attribute__((ext_vector_type(4))) float f32x4;

// ---------------- bf16 helpers ----------------
__device__ __forceinline__ float bf2f(unsigned short h){
  unsigned int u = ((unsigned int)h) << 16; return __uint_as_float(u);
}
__device__ __forceinline__ unsigned short f2bf(float f){
  unsigned int u = __float_as_uint(f);
  unsigned int r = (u + 0x7fffu + ((u >> 16) & 1u)) >> 16;   // RNE
  return (unsigned short)r;
}

// ---------------- prep kernels ----------------
__global__ void hist_dst_k(const int* __restrict__ ei, int* __restrict__ deg){
  int e = blockIdx.x*256 + threadIdx.x;
  if (e < NE) atomicAdd(&deg[ei[NE + e]], 1);
}
__global__ void dinv_k(const int* __restrict__ deg, float* __restrict__ dinv){
  int i = blockIdx.x*256 + threadIdx.x;
  if (i < NN) dinv[i] = rsqrtf((float)(deg[i] + 1));   // +1 = self loop
}
// single-block exclusive scan of deg -> row_ptr[NN+1]
__global__ void scan_k(const int* __restrict__ deg, int* __restrict__ rp){
  __shared__ int sums[1024];
  int tid = threadIdx.x;
  const int chunk = (NN + 1023)/1024;
  int b = tid*chunk, e = min(b+chunk, NN);
  int s = 0;
  for (int i=b;i<e;i++) s += deg[i];
  sums[tid] = s; __syncthreads();
  for (int off=1; off<1024; off<<=1){
    int v = (tid>=off) ? sums[tid-off] : 0;
    __syncthreads();
    sums[tid] += v;
    __syncthreads();
  }
  int run = (tid>0) ? sums[tid-1] : 0;
  for (int i=b;i<e;i++){ rp[i] = run; run += deg[i]; }
  if (tid==1023) rp[NN] = sums[1023];
}
__global__ void scatter_k(const int* __restrict__ ei, const int* __restrict__ rp,
                          int* __restrict__ cur, int* __restrict__ col){
  int e = blockIdx.x*256 + threadIdx.x;
  if (e < NE){
    int d = ei[NE + e];
    int pos = rp[d] + atomicAdd(&cur[d], 1);
    col[pos] = ei[e];
  }
}
__global__ void cnt_k(const int* __restrict__ batch, int* __restrict__ cnt){
  int i = blockIdx.x*256 + threadIdx.x;
  if (i < NN) atomicAdd(&cnt[batch[i]], 1);
}
// fp32 -> bf16 pairwise
__global__ void f2b_k(const float* __restrict__ in, unsigned short* __restrict__ out, int n2){
  int i = blockIdx.x*256 + threadIdx.x;
  if (i < n2){
    float2 v = ((const float2*)in)[i];
    unsigned int o = (unsigned int)f2bf(v.x) | ((unsigned int)f2bf(v.y) << 16);
    ((unsigned int*)out)[i] = o;
  }
}
// swizzle fp32 W[K][N] into bf16 MFMA B-fragment order:
// chunk idx = ((kt*(N/16)+nt)*4+q)*16 + l  holds B[k=kt*32+q*8+j][n=nt*16+l], j=0..7
template<int K, int N>
__global__ void wswz_k(const float* __restrict__ W, unsigned short* __restrict__ out){
  int idx = blockIdx.x*256 + threadIdx.x;
  constexpr int total = K*N/8;
  if (idx >= total) return;
  int l = idx & 15;
  int t = idx >> 4; int q = t & 3; t >>= 2;
  constexpr int NT = N/16;
  int nt = t % NT, kt = t / NT;
  int kbase = kt*32 + q*8, n = nt*16 + l;
  short8 o;
  #pragma unroll
  for (int j=0;j<8;j++) o[j] = (short)f2bf(W[(size_t)(kbase+j)*N + n]);
  *(short8*)(out + (size_t)idx*8) = o;
}

// ---------------- bf16 SpMM: out[i] = dinv[i]*(sum_nbr in[src] + in[i]) [+bias][relu] ----------------
template<int VEC> struct BV;
template<> struct BV<4>{ using LT = uint2; };
template<> struct BV<2>{ using LT = unsigned int; };
template<> struct BV<1>{ using LT = unsigned short; };

__device__ __forceinline__ void unpack(uint2 v, float* f){
  f[0]=__uint_as_float(v.x<<16); f[1]=__uint_as_float(v.x&0xffff0000u);
  f[2]=__uint_as_float(v.y<<16); f[3]=__uint_as_float(v.y&0xffff0000u);
}
__device__ __forceinline__ void unpack(unsigned int v, float* f){
  f[0]=__uint_as_float(v<<16); f[1]=__uint_as_float(v&0xffff0000u);
}
__device__ __forceinline__ void unpack(unsigned short v, float* f){
  f[0]=__uint_as_float(((unsigned int)v)<<16);
}

template<int C, bool SRC_SCALE, bool RELU, bool HAS_BIAS>
__global__ __launch_bounds__(256) void spmmb_k(const unsigned short* __restrict__ in,
    unsigned short* __restrict__ out,
    const int* __restrict__ rp, const int* __restrict__ col,
    const float* __restrict__ dinv, const float* __restrict__ bias)
{
  constexpr int VEC = C/64;
  using LT = typename BV<VEC>::LT;
  int wv = threadIdx.x >> 6, lane = threadIdx.x & 63;
  int row = blockIdx.x*4 + wv;
  if (row >= NN) return;
  int beg = rp[row], end = rp[row+1];
  float di = dinv[row];
  int co = lane*VEC;
  float acc[VEC], tmp[VEC];
  LT sv = *(const LT*)(in + (size_t)row*C + co);   // self loop
  unpack(sv, acc);
  if (SRC_SCALE){
    #pragma unroll
    for (int v=0;v<VEC;v++) acc[v] *= di;
  }
  int j = beg;
  for (; j+4 <= end; j += 4){
    int s0=col[j+0], s1=col[j+1], s2=col[j+2], s3=col[j+3];
    LT v0 = *(const LT*)(in + (size_t)s0*C + co);
    LT v1 = *(const LT*)(in + (size_t)s1*C + co);
    LT v2 = *(const LT*)(in + (size_t)s2*C + co);
    LT v3 = *(const LT*)(in + (size_t)s3*C + co);
    float w0=1.f,w1=1.f,w2=1.f,w3=1.f;
    if (SRC_SCALE){ w0=dinv[s0]; w1=dinv[s1]; w2=dinv[s2]; w3=dinv[s3]; }
    unpack(v0,tmp);
    #pragma unroll
    for (int v=0;v<VEC;v++) acc[v] = fmaf(w0, tmp[v], acc[v]);
    unpack(v1,tmp);
    #pragma unroll
    for (int v=0;v<VEC;v++) acc[v] = fmaf(w1, tmp[v], acc[v]);
    unpack(v2,tmp);
    #pragma unroll
    for (int v=0;v<VEC;v++) acc[v] = fmaf(w2, tmp[v], acc[v]);
    unpack(v3,tmp);
    #pragma unroll
    for (int v=0;v<VEC;v++) acc[v] = fmaf(w3, tmp[v], acc[v]);
  }
  for (; j < end; j++){
    int s = col[j];
    LT v = *(const LT*)(in + (size_t)s*C + co);
    float w = SRC_SCALE ? dinv[s] : 1.f;
    unpack(v,tmp);
    #pragma unroll
    for (int vv=0;vv<VEC;vv++) acc[vv] = fmaf(w, tmp[vv], acc[vv]);
  }
  #pragma unroll
  for (int v=0;v<VEC;v++){
    acc[v] *= di;
    if (HAS_BIAS) acc[v] += bias[co + v];
    if (RELU) acc[v] = fmaxf(acc[v], 0.f);
  }
  // pack + store
  if constexpr (VEC == 4){
    uint2 o;
    o.x = (unsigned int)f2bf(acc[0]) | ((unsigned int)f2bf(acc[1])<<16);
    o.y = (unsigned int)f2bf(acc[2]) | ((unsigned int)f2bf(acc[3])<<16);
    *(uint2*)(out + (size_t)row*C + co) = o;
  } else if constexpr (VEC == 2){
    unsigned int o = (unsigned int)f2bf(acc[0]) | ((unsigned int)f2bf(acc[1])<<16);
    *(unsigned int*)(out + (size_t)row*C + co) = o;
  } else {
    out[(size_t)row*C + co] = f2bf(acc[0]);
  }
}

// ---------------- MFMA bf16 GEMM: C[M,N] = A[M,K] @ W[K,N] ----------------
// EPI=0: +bias[n], relu.  EPI=1: *dinv[row].  A bf16 row-major, Bsw pre-swizzled bf16, C bf16.
// block = 4 waves; wave w handles rows blockIdx.x*64 + w*16, all N columns.
template<int K, int N, int EPI>
__global__ __launch_bounds__(256) void mgemm_k(const unsigned short* __restrict__ A,
    const unsigned short* __restrict__ Bsw,
    const float* __restrict__ aux, unsigned short* __restrict__ Cm, int M)
{
  constexpr int NT = N/16, KT = K/32;
  int w = threadIdx.x >> 6, lane = threadIdx.x & 63;
  int l = lane & 15, q = lane >> 4;
  int rowbase = blockIdx.x*64 + w*16;
  int arow = min(rowbase + l, M-1);
  f32x4 acc[NT];
  #pragma unroll
  for (int nt=0; nt<NT; nt++) acc[nt] = (f32x4){0.f,0.f,0.f,0.f};
  const unsigned short* aptr = A + (size_t)arow*K + q*8;
  const short8* bbase = (const short8*)Bsw;
  #pragma unroll
  for (int kt=0; kt<KT; kt++){
    short8 af = *(const short8*)(aptr + kt*32);
    #pragma unroll
    for (int nt=0; nt<NT; nt++){
      short8 bf = bbase[((kt*NT + nt)*4 + q)*16 + l];
      acc[nt] = __builtin_amdgcn_mfma_f32_16x16x32_bf16(af, bf, acc[nt], 0,0,0);
    }
  }
  #pragma unroll
  for (int nt=0; nt<NT; nt++){
    #pragma unroll
    for (int r=0;r<4;r++){
      int row = rowbase + q*4 + r;
      if (row < M){
        float v = acc[nt][r];
        int n = nt*16 + l;
        if (EPI == 0) v = fmaxf(v + aux[n], 0.f);
        else          v *= aux[row];
        Cm[(size_t)row*N + n] = f2bf(v);
      }
    }
  }
}

// ---------------- pooling + head ----------------
__global__ void poolb_k(const unsigned short* __restrict__ h, const int* __restrict__ batch,
                        float* __restrict__ pooled){
  int idx = blockIdx.x*256 + threadIdx.x;
  if (idx < NN*64){
    int node = idx >> 6, c = idx & 63;
    atomicAdd(&pooled[batch[node]*64 + c], bf2f(h[idx]));
  }
}
__global__ void final_k(const float* __restrict__ pooled, const int* __restrict__ cnt,
    const float* __restrict__ Wlin, const float* __restrict__ blin, float* __restrict__ out)
{
  int g = blockIdx.x*256 + threadIdx.x;
  if (g >= NG) return;
  float inv = 1.f / fmaxf((float)cnt[g], 1.f);
  float l[10];
  #pragma unroll
  for (int j=0;j<10;j++) l[j] = blin[j];
  for (int c=0;c<64;c++){
    float p = pooled[g*64 + c] * inv;
    #pragma unroll
    for (int j=0;j<10;j++) l[j] = fmaf(p, Wlin[c*10 + j], l[j]);
  }
  float mx = l[0];
  #pragma unroll
  for (int j=1;j<10;j++) mx = fmaxf(mx, l[j]);
  float e[10]; float se = 0.f;
  #pragma unroll
  for (int j=0;j<10;j++){ e[j] = expf(l[j]-mx); se += e[j]; }
  float lse = logf(se);
  #pragma unroll
  for (int j=0;j<10;j++){
    out[g*10 + j]         = l[j] - mx - lse;   // log_softmax
    out[NG*10 + g*10 + j] = e[j] / se;         // softmax
  }
}

// ---------------- launch ----------------
extern "C" void kernel_launch(void* const* d_in, const int* in_sizes, int n_in,
                              void* d_out, int out_size, void* d_ws, size_t ws_size,
                              hipStream_t stream)
{
  const float* x     = (const float*)d_in[0];
  const int*   ei    = (const int*)  d_in[1];
  const int*   batch = (const int*)  d_in[2];
  const float* W1=(const float*)d_in[4],  *b1=(const float*)d_in[5];
  const float* W2=(const float*)d_in[6],  *b2=(const float*)d_in[7];
  const float* W3=(const float*)d_in[8],  *b3=(const float*)d_in[9];
  const float* W4=(const float*)d_in[10], *b4=(const float*)d_in[11];
  const float* W5=(const float*)d_in[12], *b5=(const float*)d_in[13];
  const float* W6=(const float*)d_in[14], *b6=(const float*)d_in[15];
  const float* Wl=(const float*)d_in[16], *bl=(const float*)d_in[17];
  float* out = (float*)d_out;

  // workspace carve (bf16 era, ~143 MB)
  char* ws = (char*)d_ws;
  unsigned short* hA  = (unsigned short*)(ws + 0);            // 100000*256*2 = 51,200,000
  unsigned short* hB  = (unsigned short*)(ws + 51200000);     // 51,200,000
  unsigned short* xb  = (unsigned short*)(ws + 102400000);    // 100000*128*2 = 25,600,000
  int*   col   = (int*)  (ws + 128000000);                    // 12,800,000
  int*   rp    = (int*)  (ws + 140800000);                    // 400,016
  int*   deg   = (int*)  (ws + 141200016);                    // 400,000
  int*   cur   = (int*)  (ws + 141600016);                    // 400,000
  float* dinv  = (float*)(ws + 142000016);                    // 400,000
  float* pooled= (float*)(ws + 142400016);                    // 131,072
  int*   cnt   = (int*)  (ws + 142531088);                    // 2,048
  unsigned short* W1s = (unsigned short*)(ws + 142533136);    // 128*256*2 = 65,536
  unsigned short* W2s = (unsigned short*)(ws + 142598672);    // 256*256*2 = 131,072
  unsigned short* W3s = (unsigned short*)(ws + 142729744);    // 131,072
  unsigned short* W4s = (unsigned short*)(ws + 142860816);    // 256*128*2 = 65,536
  unsigned short* W5s = (unsigned short*)(ws + 142926352);    // 128*128*2 = 32,768
  unsigned short* W6s = (unsigned short*)(ws + 142959120);    // 128*64*2  = 16,384

  hipMemsetAsync(deg,    0, NN*4,    stream);
  hipMemsetAsync(cur,    0, NN*4,    stream);
  hipMemsetAsync(pooled, 0, NG*64*4, stream);
  hipMemsetAsync(cnt,    0, NG*4,    stream);

  const int EB = (NE + 255)/256, NB = (NN + 255)/256;
  hist_dst_k<<<EB, 256, 0, stream>>>(ei, deg);
  dinv_k    <<<NB, 256, 0, stream>>>(deg, dinv);
  scan_k    <<<1, 1024, 0, stream>>>(deg, rp);
  scatter_k <<<EB, 256, 0, stream>>>(ei, rp, cur, col);
  cnt_k     <<<NB, 256, 0, stream>>>(batch, cnt);

  // weight swizzles + x conversion
  wswz_k<128,256><<<(128*256/8 + 255)/256, 256, 0, stream>>>(W1, W1s);
  wswz_k<256,256><<<(256*256/8 + 255)/256, 256, 0, stream>>>(W2, W2s);
  wswz_k<256,256><<<(256*256/8 + 255)/256, 256, 0, stream>>>(W3, W3s);
  wswz_k<256,128><<<(256*128/8 + 255)/256, 256, 0, stream>>>(W4, W4s);
  wswz_k<128,128><<<(128*128/8 + 255)/256, 256, 0, stream>>>(W5, W5s);
  wswz_k<128, 64><<<(128*64/8  + 255)/256, 256, 0, stream>>>(W6, W6s);
  f2b_k<<<(NN*128/2 + 255)/256, 256, 0, stream>>>(x, xb, NN*128/2);

  const int SG = (NN + 3)/4;         // spmm: 4 rows/block, 1 wave/row
  const int GB = (NN + 63)/64;       // gemm: 64 rows/block

  // L1: aggregate-first at width 128 (Â x), then GEMM 128->256 (+b1, relu)
  spmmb_k<128,true,false,false><<<SG,256,0,stream>>>(xb, hA, rp, col, dinv, nullptr);
  mgemm_k<128,256,0><<<GB,256,0,stream>>>(hA, W1s, b1, hB, NN);
  // L2
  mgemm_k<256,256,1><<<GB,256,0,stream>>>(hB, W2s, dinv, hA, NN);
  spmmb_k<256,false,true,true><<<SG,256,0,stream>>>(hA, hB, rp, col, dinv, b2);
  // L3
  mgemm_k<256,256,1><<<GB,256,0,stream>>>(hB, W3s, dinv, hA, NN);
  spmmb_k<256,false,true,true><<<SG,256,0,stream>>>(hA, hB, rp, col, dinv, b3);
  // L4: 256->128
  mgemm_k<256,128,1><<<GB,256,0,stream>>>(hB, W4s, dinv, hA, NN);
  spmmb_k<128,false,true,true><<<SG,256,0,stream>>>(hA, hB, rp, col, dinv, b4);
  // L5: 128->128
  mgemm_k<128,128,1><<<GB,256,0,stream>>>(hB, W5s, dinv, hA, NN);
  spmmb_k<128,false,true,true><<<SG,256,0,stream>>>(hA, hB, rp, col, dinv, b5);
  // L6: 128->64, no relu
  mgemm_k<128,64,1><<<GB,256,0,stream>>>(hB, W6s, dinv, hA, NN);
  spmmb_k<64,false,false,true><<<SG,256,0,stream>>>(hA, hB, rp, col, dinv, b6);

  // mean pool + linear + (log_)softmax
  poolb_k<<<(NN*64 + 255)/256, 256, 0, stream>>>(hB, batch, pooled);
  final_k<<<2, 256, 0, stream>>>(pooled, cnt, Wl, bl, out);
}